// Round 9
// baseline (350.936 us; speedup 1.0000x reference)
//
#include <hip/hip_runtime.h>
#include <hip/hip_bf16.h>

#define D_IN  2048
#define D_OUT 2048
#define RNK   64
#define NE    16
#define KTOT  3072   // D_IN + NE*RNK
#define NTILE 48     // KTOT / 64

typedef __attribute__((ext_vector_type(8))) short bf16x8;
typedef __attribute__((ext_vector_type(4))) float f32x4;
typedef __attribute__((ext_vector_type(16))) float f32x16;

__device__ __forceinline__ void async_ld16(const void* g, void* l) {
    __builtin_amdgcn_global_load_lds(
        (const __attribute__((address_space(1))) void*)g,
        (__attribute__((address_space(3))) void*)l,
        16, 0, 0);
}

// ---------------------------------------------------------------------------
// K1: merged weight prep (verbatim R6).
// ---------------------------------------------------------------------------
__global__ __launch_bounds__(384) void castwa_kernel(
    const float* __restrict__ Wb, const float* __restrict__ Bm,
    const float* __restrict__ A,
    __hip_bfloat16* __restrict__ Wc, __hip_bfloat16* __restrict__ Ab)
{
    const int c = threadIdx.x * 8;
    const float* src;
    __hip_bfloat16* dst;
    if (blockIdx.x < D_OUT) {
        const int n = blockIdx.x;
        if (c < D_IN) {
            src = Wb + (size_t)n * D_IN + c;
        } else {
            const int j = c - D_IN;
            const int e = j >> 6, r = j & 63;
            src = Bm + ((size_t)e * D_OUT + n) * RNK + r;
        }
        dst = Wc + (size_t)n * KTOT + c;
    } else {
        if (c >= D_IN) return;
        const int r = blockIdx.x - D_OUT;
        src = A + (size_t)r * D_IN + c;
        dst = Ab + (size_t)r * D_IN + c;
    }
    const float4 a = *(const float4*)src;
    const float4 b = *(const float4*)(src + 4);
    const float vv[8] = {a.x, a.y, a.z, a.w, b.x, b.y, b.z, b.w};
    union { bf16x8 v; __hip_bfloat16 h[8]; } u;
#pragma unroll
    for (int q = 0; q < 8; ++q) u.h[q] = __float2bfloat16(vv[q]);
    *(bf16x8*)dst = u.v;
}

// ---------------------------------------------------------------------------
// K2 v4 (fused prep+rh, verbatim R6 — best measured config at 263.4 total).
// ---------------------------------------------------------------------------
__global__ __launch_bounds__(512) void prep2_kernel(
    const float* __restrict__ x, const float* __restrict__ Wr,
    const __hip_bfloat16* __restrict__ Ab,
    const int* __restrict__ topk_p, __hip_bfloat16* __restrict__ Xc)
{
    __shared__ __align__(16) char smem[81920];
    __hip_bfloat16* xb = (__hip_bfloat16*)smem;      // [16][2048] bf16, swizzled
    float* stg = (float*)(smem + 65536);             // [2][16][128] f32 dbuf
    float* red = (float*)smem;                       // overlay: [8][16][64] f32
    float* wf  = (float*)(smem + 65536);             // overlay: [16][16] f32

    const int tid = threadIdx.x;
    const int wave = tid >> 6, lane = tid & 63;
    const int l31 = lane & 31, lh = lane >> 5;
    const int qm = lane & 15, quad = lane >> 4;
    const int t0 = blockIdx.x * 16;
    const int tl = wave * 2 + lh;                    // local token 0..15
    const size_t myt = (size_t)t0 + tl;

    float acc[NE];
#pragma unroll
    for (int e = 0; e < NE; ++e) acc[e] = 0.f;

    const float4* x4 = (const float4*)x;
    const int sg = l31 ^ ((l31 >> 3) & 7);
    const float* wr_src = Wr + (size_t)tl * D_IN + sg * 4;

    async_ld16(wr_src, (void*)(stg + wave * 256));
    float4 xv = x4[myt * 512 + l31];
    float4 xn;

    for (int c = 0; c < 16; ++c) {
        asm volatile("s_waitcnt vmcnt(1)" ::: "memory");
        __builtin_amdgcn_sched_barrier(0);
        __builtin_amdgcn_s_barrier();
        __builtin_amdgcn_sched_barrier(0);
        if (c < 15) {
            async_ld16(wr_src + (c + 1) * 128,
                       (void*)(stg + ((c + 1) & 1) * 2048 + wave * 256));
            xn = x4[myt * 512 + (c + 1) * 32 + l31];
        }
        union { short4 v; __hip_bfloat16 h[4]; } u;
        u.h[0] = __float2bfloat16(xv.x); u.h[1] = __float2bfloat16(xv.y);
        u.h[2] = __float2bfloat16(xv.z); u.h[3] = __float2bfloat16(xv.w);
        *(short4*)(Xc + myt * KTOT + c * 128 + l31 * 4) = u.v;
        const int G = c * 16 + (l31 >> 1);
        *(short4*)((char*)xb + tl * 4096 + ((G ^ (tl & 7)) * 16)
                   + (l31 & 1) * 8) = u.v;
        const float* sb = stg + (c & 1) * 2048;
#pragma unroll
        for (int e = 0; e < NE; ++e) {
            const float4 wv = *(const float4*)(sb + e * 128 + sg * 4);
            acc[e] += xv.x * wv.x + xv.y * wv.y + xv.z * wv.z + xv.w * wv.w;
        }
        if (c < 15) xv = xn;
    }

#pragma unroll
    for (int off = 16; off; off >>= 1)
#pragma unroll
        for (int e = 0; e < NE; ++e)
            acc[e] += __shfl_xor(acc[e], off, 64);
    if (l31 == 0) {
        const int k = topk_p[0];
        float m = -1e30f;
#pragma unroll
        for (int e = 0; e < NE; ++e) m = fmaxf(m, acc[e]);
        float w[NE]; float ssum = 0.f;
#pragma unroll
        for (int e = 0; e < NE; ++e) { w[e] = __expf(acc[e] - m); ssum += w[e]; }
        const float inv = 1.f / ssum;
#pragma unroll
        for (int e = 0; e < NE; ++e) w[e] *= inv;
        float* wfout = wf + (size_t)tl * NE;
        if (k > 0 && k < NE) {
            int chosen[NE];
#pragma unroll
            for (int e = 0; e < NE; ++e) chosen[e] = 0;
            float ksum = 0.f;
            for (int it = 0; it < k; ++it) {
                int bi = 0; float bv = -1.f;
                for (int e = 0; e < NE; ++e)
                    if (!chosen[e] && w[e] > bv) { bv = w[e]; bi = e; }
                chosen[bi] = 1; ksum += bv;
            }
            const float rinv = 1.f / (ksum + 1e-6f);
            for (int e = 0; e < NE; ++e) wfout[e] = chosen[e] ? w[e] * rinv : 0.f;
        } else {
            for (int e = 0; e < NE; ++e) wfout[e] = w[e];
        }
    }
    __syncthreads();

    f32x4 racc[4] = {};
    const int kb = wave * 256;
#pragma unroll
    for (int s = 0; s < 4; ++s) {
        const int k0 = kb + s * 64;
        const int gg0 = (k0 >> 3) + quad;
        const bf16x8 a0 = *(const bf16x8*)((char*)xb + qm * 4096 + ((gg0 ^ (qm & 7)) * 16));
        const bf16x8 a1 = *(const bf16x8*)((char*)xb + qm * 4096 + (((gg0 + 4) ^ (qm & 7)) * 16));
        bf16x8 b0[4], b1[4];
#pragma unroll
        for (int nf = 0; nf < 4; ++nf) {
            const __hip_bfloat16* bp = Ab + (size_t)(qm + nf * 16) * D_IN + k0 + quad * 8;
            b0[nf] = *(const bf16x8*)bp;
            b1[nf] = *(const bf16x8*)(bp + 32);
        }
#pragma unroll
        for (int nf = 0; nf < 4; ++nf) {
            racc[nf] = __builtin_amdgcn_mfma_f32_16x16x32_bf16(a0, b0[nf], racc[nf], 0, 0, 0);
            racc[nf] = __builtin_amdgcn_mfma_f32_16x16x32_bf16(a1, b1[nf], racc[nf], 0, 0, 0);
        }
    }
    __syncthreads();

#pragma unroll
    for (int nf = 0; nf < 4; ++nf)
#pragma unroll
        for (int r = 0; r < 4; ++r)
            red[(wave * 16 + quad * 4 + r) * 64 + nf * 16 + qm] = racc[nf][r];
    __syncthreads();

#pragma unroll
    for (int it = 0; it < 4; ++it) {
        const int s = it * 512 + tid;
        const int t = s >> 7;
        const int chunk = s & 127;
        const int e = chunk >> 3, r0 = (chunk & 7) * 8;
        const float wgt = wf[t * 16 + e];
        float4 s0 = {0.f, 0.f, 0.f, 0.f}, s1 = {0.f, 0.f, 0.f, 0.f};
#pragma unroll
        for (int w2 = 0; w2 < 8; ++w2) {
            const float4 p0 = ((const float4*)red)[(w2 * 16 + t) * 16 + (r0 >> 2)];
            const float4 p1 = ((const float4*)red)[(w2 * 16 + t) * 16 + (r0 >> 2) + 1];
            s0.x += p0.x; s0.y += p0.y; s0.z += p0.z; s0.w += p0.w;
            s1.x += p1.x; s1.y += p1.y; s1.z += p1.z; s1.w += p1.w;
        }
        union { bf16x8 v; __hip_bfloat16 h[8]; } u;
        u.h[0] = __float2bfloat16(wgt * s0.x); u.h[1] = __float2bfloat16(wgt * s0.y);
        u.h[2] = __float2bfloat16(wgt * s0.z); u.h[3] = __float2bfloat16(wgt * s0.w);
        u.h[4] = __float2bfloat16(wgt * s1.x); u.h[5] = __float2bfloat16(wgt * s1.y);
        u.h[6] = __float2bfloat16(wgt * s1.z); u.h[7] = __float2bfloat16(wgt * s1.w);
        *(bf16x8*)(Xc + (size_t)(t0 + t) * KTOT + D_IN + chunk * 8) = u.v;
    }
}

// ---------------------------------------------------------------------------
// K4 (gemm5, R7 schedule): split into TWO half-grids (bn 0-3, 4-7) purely so
// prep2 surfaces in the top-5 rocprof table with full counters. Halves write
// disjoint C columns; per-half 2D XCD map keeps A-panel locality.
// ---------------------------------------------------------------------------
#define LDA3(BUF, M, ks) (*(const bf16x8*)(smem + (BUF) + \
    ((((M) >> 1) * 128 + wm2 * 64 + ((M) & 1) * 32 + l31) * 128) + \
    (((((ks) * 2 + lhi) ^ (l31 & 7))) << 4)))
#define LDB3(BUF, N, ks) (*(const bf16x8*)(smem + 65536 + (BUF) + \
    ((wn4 * 64 + (N) * 32 + l31) * 128) + \
    (((((ks) * 2 + lhi) ^ (l31 & 7))) << 4)))

#define GP(BUF, MH, ISSUE, WAIT) do { \
    bf16x8 af[2][4]; \
    if ((MH) == 0) { \
        _Pragma("unroll") for (int n = 0; n < 2; ++n) \
        _Pragma("unroll") for (int ks = 0; ks < 4; ++ks) \
            bfr[n][ks] = LDB3(BUF, n, ks); \
    } \
    _Pragma("unroll") for (int m = 0; m < 2; ++m) \
    _Pragma("unroll") for (int ks = 0; ks < 4; ++ks) \
        af[m][ks] = LDA3(BUF, (MH) * 2 + m, ks); \
    ISSUE; \
    WAIT; \
    __builtin_amdgcn_sched_barrier(0); \
    __builtin_amdgcn_s_barrier(); \
    asm volatile("s_waitcnt lgkmcnt(0)" ::: "memory"); \
    __builtin_amdgcn_sched_barrier(0); \
    __builtin_amdgcn_s_setprio(1); \
    _Pragma("unroll") for (int ks = 0; ks < 4; ++ks) \
    _Pragma("unroll") for (int m = 0; m < 2; ++m) \
    _Pragma("unroll") for (int n = 0; n < 2; ++n) \
        acc[(MH) * 2 + m][n] = __builtin_amdgcn_mfma_f32_32x32x16_bf16( \
            af[m][ks], bfr[n][ks], acc[(MH) * 2 + m][n], 0, 0, 0); \
    __builtin_amdgcn_s_setprio(0); \
    __builtin_amdgcn_sched_barrier(0); \
    __builtin_amdgcn_s_barrier(); \
    __builtin_amdgcn_sched_barrier(0); \
} while (0)

__global__ __launch_bounds__(512, 1) void gemm5_kernel(
    const __hip_bfloat16* __restrict__ Am,
    const __hip_bfloat16* __restrict__ Bm,
    const float* __restrict__ bias,
    float* __restrict__ C, int bnoff)
{
    __shared__ __align__(16) char smem[131072];
    const int tid = threadIdx.x;
    const int w = tid >> 6, lane = tid & 63;
    const int l31 = lane & 31, lhi = lane >> 5;
    const int wm2 = w >> 2, wn4 = w & 3;

    // per-half 2D XCD map: 128 blocks; xcd owns bm in [(xcd&3)*8,+8),
    // bn in bnoff + (xcd>>2)*2 + {0,1}
    const int flat = blockIdx.y * gridDim.x + blockIdx.x;
    const int xcd = flat & 7, j = flat >> 3;          // j in [0,16)
    const int bm = (xcd & 3) * 8 + (j & 7);
    const int bn = bnoff + (xcd >> 2) * 2 + (j >> 3);

    const int rb0 = w * 16 + (lane >> 3);
    const int rb1 = rb0 + 8;
    const int gs0 = (lane & 7) ^ (rb0 & 7);
    const int gs1 = (lane & 7) ^ (rb1 & 7);
    const __hip_bfloat16* pA0 = Am + (size_t)(bm * 256 + rb0) * KTOT + gs0 * 8;
    const __hip_bfloat16* pA1 = Am + (size_t)(bm * 256 + rb1) * KTOT + gs1 * 8;
    const __hip_bfloat16* pB0 = Bm + (size_t)(bn * 256 + rb0) * KTOT + gs0 * 8;
    const __hip_bfloat16* pB1 = Bm + (size_t)(bn * 256 + rb1) * KTOT + gs1 * 8;
    const size_t HO = (size_t)128 * KTOT;

    f32x16 acc[4][2] = {};
    bf16x8 bfr[2][4];

    auto stageP1 = [&](int tn) {
        const size_t ko = (size_t)tn * 64;
        char* da = smem + (tn & 1) * 32768 + w * 2048;
        async_ld16(pA0 + ko, da);
        async_ld16(pA1 + ko, da + 1024);
        char* db = smem + 65536 + (tn & 1) * 32768 + w * 2048;
        async_ld16(pB0 + ko, db);
        async_ld16(pB1 + ko, db + 1024);
        async_ld16(pB0 + HO + ko, db + 16384);
        async_ld16(pB1 + HO + ko, db + 16384 + 1024);
    };
    auto stageP2 = [&](int tn) {
        const size_t ko = (size_t)tn * 64;
        char* da = smem + (tn & 1) * 32768 + 16384 + w * 2048;
        async_ld16(pA0 + HO + ko, da);
        async_ld16(pA1 + HO + ko, da + 1024);
    };

    stageP1(0); stageP2(0); stageP1(1);
    asm volatile("s_waitcnt vmcnt(8)" ::: "memory");
    __builtin_amdgcn_sched_barrier(0);
    __builtin_amdgcn_s_barrier();
    __builtin_amdgcn_sched_barrier(0);

    for (int t = 0; t < NTILE - 2; ++t) {
        const int bo = (t & 1) * 32768;
        GP(bo, 0, stageP2(t + 1),
           asm volatile("s_waitcnt vmcnt(8)" ::: "memory"));
        GP(bo, 1, stageP1(t + 2),
           asm volatile("s_waitcnt vmcnt(8)" ::: "memory"));
    }
    {
        const int bo = ((NTILE - 2) & 1) * 32768;
        GP(bo, 0, stageP2(NTILE - 1),
           asm volatile("s_waitcnt vmcnt(8)" ::: "memory"));
        GP(bo, 1, ,
           asm volatile("s_waitcnt vmcnt(2)" ::: "memory"));
    }
    {
        const int bo = ((NTILE - 1) & 1) * 32768;
        GP(bo, 0, ,
           asm volatile("s_waitcnt vmcnt(0)" ::: "memory"));
        GP(bo, 1, , );
    }

#pragma unroll
    for (int n = 0; n < 2; ++n) {
        const int col = bn * 256 + wn4 * 64 + n * 32 + l31;
        const float bbv = bias[col];
#pragma unroll
        for (int m = 0; m < 4; ++m) {
            const size_t rbase = (size_t)bm * 256 + (m >> 1) * 128 + wm2 * 64
                               + (m & 1) * 32 + 4 * lhi;
#pragma unroll
            for (int reg = 0; reg < 16; ++reg) {
                const size_t row = rbase + (reg & 3) + 8 * (reg >> 2);
                C[row * D_OUT + col] = acc[m][n][reg] + bbv;
            }
        }
    }
}

extern "C" void kernel_launch(void* const* d_in, const int* in_sizes, int n_in,
                              void* d_out, int out_size, void* d_ws, size_t ws_size,
                              hipStream_t stream) {
    const float* x    = (const float*)d_in[0];
    const float* Wb   = (const float*)d_in[1];
    const float* bb   = (const float*)d_in[2];
    const float* A    = (const float*)d_in[3];
    const float* Bm   = (const float*)d_in[4];
    const float* Wr   = (const float*)d_in[5];
    const int*   topk = (const int*)d_in[6];
    float* out = (float*)d_out;
    const int T = in_sizes[0] / D_IN;   // 8192 tokens

    __hip_bfloat16* Xc = (__hip_bfloat16*)d_ws;                                 // T*KTOT bf16 (48MB)
    __hip_bfloat16* Wc = (__hip_bfloat16*)((char*)d_ws + (size_t)T * KTOT * 2); // D_OUT*KTOT bf16 (12MB)
    // Parked in d_out (fully overwritten by the final GEMM):
    __hip_bfloat16* Ab = (__hip_bfloat16*)d_out;              // 256 KB at front

    castwa_kernel<<<D_OUT + RNK, 384, 0, stream>>>(Wb, Bm, A, Wc, Ab);
    prep2_kernel<<<T / 16, 512, 0, stream>>>(x, Wr, Ab, topk, Xc);
    gemm5_kernel<<<dim3(32, 4), 512, 0, stream>>>(Xc, Wc, bb, out, 0);
    gemm5_kernel<<<dim3(32, 4), 512, 0, stream>>>(Xc, Wc, bb, out, 4);
}

// Round 10
// 256.746 us; speedup vs baseline: 1.3669x; 1.3669x over previous
//
#include <hip/hip_runtime.h>
#include <hip/hip_bf16.h>

#define D_IN  2048
#define D_OUT 2048
#define RNK   64
#define NE    16
#define KTOT  3072   // D_IN + NE*RNK
#define NTILE 48     // KTOT / 64

typedef __attribute__((ext_vector_type(8))) short bf16x8;
typedef __attribute__((ext_vector_type(4))) float f32x4;
typedef __attribute__((ext_vector_type(16))) float f32x16;

__device__ __forceinline__ void async_ld16(const void* g, void* l) {
    __builtin_amdgcn_global_load_lds(
        (const __attribute__((address_space(1))) void*)g,
        (__attribute__((address_space(3))) void*)l,
        16, 0, 0);
}

// ---------------------------------------------------------------------------
// K1: merged weight prep.
//  blocks [0,2048):   Wc row n = [ W_base | B' ], B'[n][e*64+r] = B[e][n][r]
//  blocks [2048,2112): Abp = bf16(A) PACKED IN MFMA B-FRAGMENT LANE ORDER:
//    Abp[((K0*4+nf)*2+half)*512 + lane*8 + j] =
//        A[(lane&15)+nf*16][K0*64 + half*32 + (lane>>4)*8 + j]
//    so prep2 phase 2 reads one coalesced 1KB line per B-frag instruction
//    instead of 64 scattered 16B requests (the ~100us invariant).
// ---------------------------------------------------------------------------
__global__ __launch_bounds__(384) void castwa_kernel(
    const float* __restrict__ Wb, const float* __restrict__ Bm,
    const float* __restrict__ A,
    __hip_bfloat16* __restrict__ Wc, __hip_bfloat16* __restrict__ Abp)
{
    const int c = threadIdx.x * 8;
    const float* src;
    __hip_bfloat16* dst;
    if (blockIdx.x < D_OUT) {
        const int n = blockIdx.x;
        if (c < D_IN) {
            src = Wb + (size_t)n * D_IN + c;
        } else {
            const int j = c - D_IN;
            const int e = j >> 6, r = j & 63;
            src = Bm + ((size_t)e * D_OUT + n) * RNK + r;
        }
        dst = Wc + (size_t)n * KTOT + c;
    } else {
        if (c >= D_IN) return;
        const int r = blockIdx.x - D_OUT;          // A row 0..63
        src = A + (size_t)r * D_IN + c;
        const int K0 = c >> 6, half = (c >> 5) & 1, q = (c >> 3) & 3;
        const int nf = r >> 4, n = r & 15;
        dst = Abp + ((size_t)((K0 * 4 + nf) * 2 + half) * 512)
                  + (q * 16 + n) * 8;
    }
    const float4 a = *(const float4*)src;
    const float4 b = *(const float4*)(src + 4);
    const float vv[8] = {a.x, a.y, a.z, a.w, b.x, b.y, b.z, b.w};
    union { bf16x8 v; __hip_bfloat16 h[8]; } u;
#pragma unroll
    for (int q = 0; q < 8; ++q) u.h[q] = __float2bfloat16(vv[q]);
    *(bf16x8*)dst = u.v;
}

// ---------------------------------------------------------------------------
// K2 v5 (fused prep+rh): R6's verified structure; ONLY phase 2's B-frag
// loads changed to the packed-coalesced Abp layout (per-lane content
// bit-identical to the old scattered reads).
// ---------------------------------------------------------------------------
__global__ __launch_bounds__(512) void prep2_kernel(
    const float* __restrict__ x, const float* __restrict__ Wr,
    const __hip_bfloat16* __restrict__ Abp,
    const int* __restrict__ topk_p, __hip_bfloat16* __restrict__ Xc)
{
    __shared__ __align__(16) char smem[81920];
    __hip_bfloat16* xb = (__hip_bfloat16*)smem;      // [16][2048] bf16, swizzled
    float* stg = (float*)(smem + 65536);             // [2][16][128] f32 dbuf
    float* red = (float*)smem;                       // overlay: [8][16][64] f32
    float* wf  = (float*)(smem + 65536);             // overlay: [16][16] f32

    const int tid = threadIdx.x;
    const int wave = tid >> 6, lane = tid & 63;
    const int l31 = lane & 31, lh = lane >> 5;
    const int qm = lane & 15, quad = lane >> 4;
    const int t0 = blockIdx.x * 16;
    const int tl = wave * 2 + lh;                    // local token 0..15
    const size_t myt = (size_t)t0 + tl;

    float acc[NE];
#pragma unroll
    for (int e = 0; e < NE; ++e) acc[e] = 0.f;

    const float4* x4 = (const float4*)x;
    const int sg = l31 ^ ((l31 >> 3) & 7);
    const float* wr_src = Wr + (size_t)tl * D_IN + sg * 4;

    async_ld16(wr_src, (void*)(stg + wave * 256));
    float4 xv = x4[myt * 512 + l31];
    float4 xn;

    for (int c = 0; c < 16; ++c) {
        asm volatile("s_waitcnt vmcnt(1)" ::: "memory");
        __builtin_amdgcn_sched_barrier(0);
        __builtin_amdgcn_s_barrier();
        __builtin_amdgcn_sched_barrier(0);
        if (c < 15) {
            async_ld16(wr_src + (c + 1) * 128,
                       (void*)(stg + ((c + 1) & 1) * 2048 + wave * 256));
            xn = x4[myt * 512 + (c + 1) * 32 + l31];
        }
        union { short4 v; __hip_bfloat16 h[4]; } u;
        u.h[0] = __float2bfloat16(xv.x); u.h[1] = __float2bfloat16(xv.y);
        u.h[2] = __float2bfloat16(xv.z); u.h[3] = __float2bfloat16(xv.w);
        *(short4*)(Xc + myt * KTOT + c * 128 + l31 * 4) = u.v;
        const int G = c * 16 + (l31 >> 1);
        *(short4*)((char*)xb + tl * 4096 + ((G ^ (tl & 7)) * 16)
                   + (l31 & 1) * 8) = u.v;
        const float* sb = stg + (c & 1) * 2048;
#pragma unroll
        for (int e = 0; e < NE; ++e) {
            const float4 wv = *(const float4*)(sb + e * 128 + sg * 4);
            acc[e] += xv.x * wv.x + xv.y * wv.y + xv.z * wv.z + xv.w * wv.w;
        }
        if (c < 15) xv = xn;
    }

#pragma unroll
    for (int off = 16; off; off >>= 1)
#pragma unroll
        for (int e = 0; e < NE; ++e)
            acc[e] += __shfl_xor(acc[e], off, 64);
    if (l31 == 0) {
        const int k = topk_p[0];
        float m = -1e30f;
#pragma unroll
        for (int e = 0; e < NE; ++e) m = fmaxf(m, acc[e]);
        float w[NE]; float ssum = 0.f;
#pragma unroll
        for (int e = 0; e < NE; ++e) { w[e] = __expf(acc[e] - m); ssum += w[e]; }
        const float inv = 1.f / ssum;
#pragma unroll
        for (int e = 0; e < NE; ++e) w[e] *= inv;
        float* wfout = wf + (size_t)tl * NE;
        if (k > 0 && k < NE) {
            int chosen[NE];
#pragma unroll
            for (int e = 0; e < NE; ++e) chosen[e] = 0;
            float ksum = 0.f;
            for (int it = 0; it < k; ++it) {
                int bi = 0; float bv = -1.f;
                for (int e = 0; e < NE; ++e)
                    if (!chosen[e] && w[e] > bv) { bv = w[e]; bi = e; }
                chosen[bi] = 1; ksum += bv;
            }
            const float rinv = 1.f / (ksum + 1e-6f);
            for (int e = 0; e < NE; ++e) wfout[e] = chosen[e] ? w[e] * rinv : 0.f;
        } else {
            for (int e = 0; e < NE; ++e) wfout[e] = w[e];
        }
    }
    __syncthreads();

    // ---- phase 2: RH MFMA; wave w covers K slice [w*256, w*256+256) ----
    // B-frags now from packed Abp: one coalesced 1KB read per instruction.
    f32x4 racc[4] = {};
#pragma unroll
    for (int s = 0; s < 4; ++s) {
        const int k0 = wave * 256 + s * 64;
        const int K0 = wave * 4 + s;
        const int gg0 = (k0 >> 3) + quad;
        const bf16x8 a0 = *(const bf16x8*)((char*)xb + qm * 4096 + ((gg0 ^ (qm & 7)) * 16));
        const bf16x8 a1 = *(const bf16x8*)((char*)xb + qm * 4096 + (((gg0 + 4) ^ (qm & 7)) * 16));
        bf16x8 b0[4], b1[4];
#pragma unroll
        for (int nf = 0; nf < 4; ++nf) {
            const __hip_bfloat16* bp = Abp
                + ((size_t)((K0 * 4 + nf) * 2) * 512) + lane * 8;
            b0[nf] = *(const bf16x8*)bp;
            b1[nf] = *(const bf16x8*)(bp + 512);
        }
#pragma unroll
        for (int nf = 0; nf < 4; ++nf) {
            racc[nf] = __builtin_amdgcn_mfma_f32_16x16x32_bf16(a0, b0[nf], racc[nf], 0, 0, 0);
            racc[nf] = __builtin_amdgcn_mfma_f32_16x16x32_bf16(a1, b1[nf], racc[nf], 0, 0, 0);
        }
    }
    __syncthreads();

#pragma unroll
    for (int nf = 0; nf < 4; ++nf)
#pragma unroll
        for (int r = 0; r < 4; ++r)
            red[(wave * 16 + quad * 4 + r) * 64 + nf * 16 + qm] = racc[nf][r];
    __syncthreads();

#pragma unroll
    for (int it = 0; it < 4; ++it) {
        const int s = it * 512 + tid;
        const int t = s >> 7;
        const int chunk = s & 127;
        const int e = chunk >> 3, r0 = (chunk & 7) * 8;
        const float wgt = wf[t * 16 + e];
        float4 s0 = {0.f, 0.f, 0.f, 0.f}, s1 = {0.f, 0.f, 0.f, 0.f};
#pragma unroll
        for (int w2 = 0; w2 < 8; ++w2) {
            const float4 p0 = ((const float4*)red)[(w2 * 16 + t) * 16 + (r0 >> 2)];
            const float4 p1 = ((const float4*)red)[(w2 * 16 + t) * 16 + (r0 >> 2) + 1];
            s0.x += p0.x; s0.y += p0.y; s0.z += p0.z; s0.w += p0.w;
            s1.x += p1.x; s1.y += p1.y; s1.z += p1.z; s1.w += p1.w;
        }
        union { bf16x8 v; __hip_bfloat16 h[8]; } u;
        u.h[0] = __float2bfloat16(wgt * s0.x); u.h[1] = __float2bfloat16(wgt * s0.y);
        u.h[2] = __float2bfloat16(wgt * s0.z); u.h[3] = __float2bfloat16(wgt * s0.w);
        u.h[4] = __float2bfloat16(wgt * s1.x); u.h[5] = __float2bfloat16(wgt * s1.y);
        u.h[6] = __float2bfloat16(wgt * s1.z); u.h[7] = __float2bfloat16(wgt * s1.w);
        *(bf16x8*)(Xc + (size_t)(t0 + t) * KTOT + D_IN + chunk * 8) = u.v;
    }
}

// ---------------------------------------------------------------------------
// K4 (gemm5): single dispatch again (R7 config, measured ~113.3us). Control.
// ---------------------------------------------------------------------------
#define LDA3(BUF, M, ks) (*(const bf16x8*)(smem + (BUF) + \
    ((((M) >> 1) * 128 + wm2 * 64 + ((M) & 1) * 32 + l31) * 128) + \
    (((((ks) * 2 + lhi) ^ (l31 & 7))) << 4)))
#define LDB3(BUF, N, ks) (*(const bf16x8*)(smem + 65536 + (BUF) + \
    ((wn4 * 64 + (N) * 32 + l31) * 128) + \
    (((((ks) * 2 + lhi) ^ (l31 & 7))) << 4)))

#define GP(BUF, MH, ISSUE, WAIT) do { \
    bf16x8 af[2][4]; \
    if ((MH) == 0) { \
        _Pragma("unroll") for (int n = 0; n < 2; ++n) \
        _Pragma("unroll") for (int ks = 0; ks < 4; ++ks) \
            bfr[n][ks] = LDB3(BUF, n, ks); \
    } \
    _Pragma("unroll") for (int m = 0; m < 2; ++m) \
    _Pragma("unroll") for (int ks = 0; ks < 4; ++ks) \
        af[m][ks] = LDA3(BUF, (MH) * 2 + m, ks); \
    ISSUE; \
    WAIT; \
    __builtin_amdgcn_sched_barrier(0); \
    __builtin_amdgcn_s_barrier(); \
    asm volatile("s_waitcnt lgkmcnt(0)" ::: "memory"); \
    __builtin_amdgcn_sched_barrier(0); \
    __builtin_amdgcn_s_setprio(1); \
    _Pragma("unroll") for (int ks = 0; ks < 4; ++ks) \
    _Pragma("unroll") for (int m = 0; m < 2; ++m) \
    _Pragma("unroll") for (int n = 0; n < 2; ++n) \
        acc[(MH) * 2 + m][n] = __builtin_amdgcn_mfma_f32_32x32x16_bf16( \
            af[m][ks], bfr[n][ks], acc[(MH) * 2 + m][n], 0, 0, 0); \
    __builtin_amdgcn_s_setprio(0); \
    __builtin_amdgcn_sched_barrier(0); \
    __builtin_amdgcn_s_barrier(); \
    __builtin_amdgcn_sched_barrier(0); \
} while (0)

__global__ __launch_bounds__(512, 1) void gemm5_kernel(
    const __hip_bfloat16* __restrict__ Am,
    const __hip_bfloat16* __restrict__ Bm,
    const float* __restrict__ bias,
    float* __restrict__ C)
{
    __shared__ __align__(16) char smem[131072];
    const int tid = threadIdx.x;
    const int w = tid >> 6, lane = tid & 63;
    const int l31 = lane & 31, lhi = lane >> 5;
    const int wm2 = w >> 2, wn4 = w & 3;

    const int flat = blockIdx.y * gridDim.x + blockIdx.x;
    const int xcd = flat & 7, j = flat >> 3;
    const int bm = (xcd & 3) * 8 + (j & 7);
    const int bn = (xcd >> 2) * 4 + (j >> 3);

    const int rb0 = w * 16 + (lane >> 3);
    const int rb1 = rb0 + 8;
    const int gs0 = (lane & 7) ^ (rb0 & 7);
    const int gs1 = (lane & 7) ^ (rb1 & 7);
    const __hip_bfloat16* pA0 = Am + (size_t)(bm * 256 + rb0) * KTOT + gs0 * 8;
    const __hip_bfloat16* pA1 = Am + (size_t)(bm * 256 + rb1) * KTOT + gs1 * 8;
    const __hip_bfloat16* pB0 = Bm + (size_t)(bn * 256 + rb0) * KTOT + gs0 * 8;
    const __hip_bfloat16* pB1 = Bm + (size_t)(bn * 256 + rb1) * KTOT + gs1 * 8;
    const size_t HO = (size_t)128 * KTOT;

    f32x16 acc[4][2] = {};
    bf16x8 bfr[2][4];

    auto stageP1 = [&](int tn) {
        const size_t ko = (size_t)tn * 64;
        char* da = smem + (tn & 1) * 32768 + w * 2048;
        async_ld16(pA0 + ko, da);
        async_ld16(pA1 + ko, da + 1024);
        char* db = smem + 65536 + (tn & 1) * 32768 + w * 2048;
        async_ld16(pB0 + ko, db);
        async_ld16(pB1 + ko, db + 1024);
        async_ld16(pB0 + HO + ko, db + 16384);
        async_ld16(pB1 + HO + ko, db + 16384 + 1024);
    };
    auto stageP2 = [&](int tn) {
        const size_t ko = (size_t)tn * 64;
        char* da = smem + (tn & 1) * 32768 + 16384 + w * 2048;
        async_ld16(pA0 + HO + ko, da);
        async_ld16(pA1 + HO + ko, da + 1024);
    };

    stageP1(0); stageP2(0); stageP1(1);
    asm volatile("s_waitcnt vmcnt(8)" ::: "memory");
    __builtin_amdgcn_sched_barrier(0);
    __builtin_amdgcn_s_barrier();
    __builtin_amdgcn_sched_barrier(0);

    for (int t = 0; t < NTILE - 2; ++t) {
        const int bo = (t & 1) * 32768;
        GP(bo, 0, stageP2(t + 1),
           asm volatile("s_waitcnt vmcnt(8)" ::: "memory"));
        GP(bo, 1, stageP1(t + 2),
           asm volatile("s_waitcnt vmcnt(8)" ::: "memory"));
    }
    {
        const int bo = ((NTILE - 2) & 1) * 32768;
        GP(bo, 0, stageP2(NTILE - 1),
           asm volatile("s_waitcnt vmcnt(8)" ::: "memory"));
        GP(bo, 1, ,
           asm volatile("s_waitcnt vmcnt(2)" ::: "memory"));
    }
    {
        const int bo = ((NTILE - 1) & 1) * 32768;
        GP(bo, 0, ,
           asm volatile("s_waitcnt vmcnt(0)" ::: "memory"));
        GP(bo, 1, , );
    }

#pragma unroll
    for (int n = 0; n < 2; ++n) {
        const int col = bn * 256 + wn4 * 64 + n * 32 + l31;
        const float bbv = bias[col];
#pragma unroll
        for (int m = 0; m < 4; ++m) {
            const size_t rbase = (size_t)bm * 256 + (m >> 1) * 128 + wm2 * 64
                               + (m & 1) * 32 + 4 * lhi;
#pragma unroll
            for (int reg = 0; reg < 16; ++reg) {
                const size_t row = rbase + (reg & 3) + 8 * (reg >> 2);
                C[row * D_OUT + col] = acc[m][n][reg] + bbv;
            }
        }
    }
}

extern "C" void kernel_launch(void* const* d_in, const int* in_sizes, int n_in,
                              void* d_out, int out_size, void* d_ws, size_t ws_size,
                              hipStream_t stream) {
    const float* x    = (const float*)d_in[0];
    const float* Wb   = (const float*)d_in[1];
    const float* bb   = (const float*)d_in[2];
    const float* A    = (const float*)d_in[3];
    const float* Bm   = (const float*)d_in[4];
    const float* Wr   = (const float*)d_in[5];
    const int*   topk = (const int*)d_in[6];
    float* out = (float*)d_out;
    const int T = in_sizes[0] / D_IN;   // 8192 tokens

    __hip_bfloat16* Xc = (__hip_bfloat16*)d_ws;                                 // T*KTOT bf16 (48MB)
    __hip_bfloat16* Wc = (__hip_bfloat16*)((char*)d_ws + (size_t)T * KTOT * 2); // D_OUT*KTOT bf16 (12MB)
    // Parked in d_out (fully overwritten by the final GEMM):
    __hip_bfloat16* Abp = (__hip_bfloat16*)d_out;             // 256 KB packed A

    castwa_kernel<<<D_OUT + RNK, 384, 0, stream>>>(Wb, Bm, A, Wc, Abp);
    prep2_kernel<<<T / 16, 512, 0, stream>>>(x, Wr, Abp, topk, Xc);
    gemm5_kernel<<<dim3(32, 8), 512, 0, stream>>>(Xc, Wc, bb, out);
}